// Round 1
// baseline (44.651 us; speedup 1.0000x reference)
//
#include <hip/hip_runtime.h>
#include <hip/hip_bf16.h>

#define DIN  1024
#define DOUT 1024
#define MROWS 8192   // B*S = 4*2048

#define BM 128
#define BN 128
#define BK 32
#define KTILES (DIN / BK)   // 32

typedef __attribute__((ext_vector_type(8))) short short8;
typedef __attribute__((ext_vector_type(4))) float f32x4;

__device__ __forceinline__ ushort f2bf(float f) {
    union { float f; unsigned u; } x; x.f = f;
    unsigned u = x.u + 0x7fffu + ((x.u >> 16) & 1u);  // RNE
    return (ushort)(u >> 16);
}

// ---------- pass 1a: X f32 -> bf16 (layout preserved) ----------
__global__ void cvt_x_kernel(const float* __restrict__ X, ushort* __restrict__ Xb, int n4) {
    int i = blockIdx.x * blockDim.x + threadIdx.x;
    int stride = gridDim.x * blockDim.x;
    const float4* X4 = (const float4*)X;
    ushort4* O4 = (ushort4*)Xb;
    for (int idx = i; idx < n4; idx += stride) {
        float4 v = X4[idx];
        ushort4 o;
        o.x = f2bf(v.x); o.y = f2bf(v.y); o.z = f2bf(v.z); o.w = f2bf(v.w);
        O4[idx] = o;
    }
}

// ---------- pass 1b: Wv [K][N] f32 -> WvT [N][K] bf16 (tiled transpose) ----------
__global__ void cvt_wt_kernel(const float* __restrict__ W, ushort* __restrict__ Wt) {
    __shared__ float tile[32][33];
    int bx = blockIdx.x * 32;  // n base
    int by = blockIdx.y * 32;  // k base
    int tx = threadIdx.x;      // 0..31
    int ty = threadIdx.y;      // 0..7
#pragma unroll
    for (int i = 0; i < 32; i += 8)
        tile[ty + i][tx] = W[(size_t)(by + ty + i) * DOUT + (bx + tx)];
    __syncthreads();
#pragma unroll
    for (int i = 0; i < 32; i += 8)
        Wt[(size_t)(bx + ty + i) * DIN + (by + tx)] = f2bf(tile[tx][ty + i]);
}

// ---------- pass 2: C[M][N] = Xb[M][K] @ WvT[N][K]^T + bias ----------
__global__ __launch_bounds__(256, 2) void gemm_bias(
    const ushort* __restrict__ Xb,    // [8192][1024] bf16
    const ushort* __restrict__ Wt,    // [1024 n][1024 k] bf16
    const float* __restrict__ bias,   // [1024]
    float* __restrict__ out)          // [8192][1024] f32
{
    __shared__ ushort As[2][BM * BK];   // [128][32], row stride 32 (64 B)
    __shared__ ushort Bs[2][BN * BK];

    const int tid  = threadIdx.x;
    const int lane = tid & 63;
    const int wid  = tid >> 6;     // 0..3
    const int wr   = wid >> 1;     // 0..1  (wave row)
    const int wc   = wid & 1;      // 0..1  (wave col)

    // XCD-aware bijective swizzle: 512 blocks = 8 XCDs x 64; each XCD gets
    // 8 contiguous m-tile rows x all 8 n-tiles -> A panel (2MB) + Wt (2MB) = L2-fit.
    const int bid = blockIdx.x;
    const int swz = (bid & 7) * 64 + (bid >> 3);
    const int bm = (swz >> 3) * BM;
    const int bn = (swz & 7) * BN;

    // ---- staging: global_load_lds width 16, linear LDS, 2 calls/wave/tile ----
    auto stageA = [&](ushort* dst, int kt) {
        const int k0 = kt * BK;
#pragma unroll
        for (int j = 0; j < 2; ++j) {
            const int cb = (wid * 2 + j) * 64;          // wave-uniform chunk base
            const int chunk = cb + lane;                // 16B chunk index
            const int row = chunk >> 2;                 // 4 chunks per 64B row
            const int col = (chunk & 3) * 8;            // ushort offset in row
            __builtin_amdgcn_global_load_lds(
                (const __attribute__((address_space(1))) void*)(Xb + (size_t)(bm + row) * DIN + k0 + col),
                (__attribute__((address_space(3))) void*)(dst + cb * 8),
                16, 0, 0);
        }
    };
    auto stageB = [&](ushort* dst, int kt) {
        const int k0 = kt * BK;
#pragma unroll
        for (int j = 0; j < 2; ++j) {
            const int cb = (wid * 2 + j) * 64;
            const int chunk = cb + lane;
            const int row = chunk >> 2;
            const int col = (chunk & 3) * 8;
            __builtin_amdgcn_global_load_lds(
                (const __attribute__((address_space(1))) void*)(Wt + (size_t)(bn + row) * DIN + k0 + col),
                (__attribute__((address_space(3))) void*)(dst + cb * 8),
                16, 0, 0);
        }
    };

    f32x4 acc[4][4];
#pragma unroll
    for (int i = 0; i < 4; ++i)
#pragma unroll
        for (int j = 0; j < 4; ++j)
            acc[i][j] = (f32x4){0.f, 0.f, 0.f, 0.f};

    auto compute = [&](const ushort* A_, const ushort* B_) {
        const int kgrp = (lane >> 4) * 8;   // k offset: 0,8,16,24
        short8 af[4], bf[4];
#pragma unroll
        for (int i = 0; i < 4; ++i) {
            const int ar = wr * 64 + i * 16 + (lane & 15);
            af[i] = *(const short8*)(A_ + ar * BK + kgrp);
            const int br = wc * 64 + i * 16 + (lane & 15);
            bf[i] = *(const short8*)(B_ + br * BK + kgrp);
        }
#pragma unroll
        for (int i = 0; i < 4; ++i)
#pragma unroll
            for (int j = 0; j < 4; ++j)
                acc[i][j] = __builtin_amdgcn_mfma_f32_16x16x32_bf16(af[i], bf[j], acc[i][j], 0, 0, 0);
    };

    // prologue
    stageA(As[0], 0);
    stageB(Bs[0], 0);
    __syncthreads();

    int cur = 0;
    for (int kt = 0; kt < KTILES - 1; ++kt) {
        stageA(As[cur ^ 1], kt + 1);
        stageB(Bs[cur ^ 1], kt + 1);
        compute(As[cur], Bs[cur]);
        __syncthreads();
        cur ^= 1;
    }
    compute(As[cur], Bs[cur]);

    // ---- epilogue: bias + store. C/D layout: col = lane&15, row = (lane>>4)*4 + r ----
    const int crow = bm + wr * 64;
    const int ccol = bn + wc * 64;
#pragma unroll
    for (int j = 0; j < 4; ++j) {
        const int col = ccol + j * 16 + (lane & 15);
        const float bval = bias[col];
#pragma unroll
        for (int i = 0; i < 4; ++i) {
            const int row0 = crow + i * 16 + (lane >> 4) * 4;
#pragma unroll
            for (int r = 0; r < 4; ++r)
                out[(size_t)(row0 + r) * DOUT + col] = acc[i][j][r] + bval;
        }
    }
}

// ---------- fallback (only if workspace too small): naive f32 ----------
__global__ void gemm_naive(const float* __restrict__ X, const float* __restrict__ W,
                           const float* __restrict__ b, float* __restrict__ out) {
    int n = blockIdx.x * blockDim.x + threadIdx.x;
    int m = blockIdx.y;
    float acc = b[n];
    for (int k = 0; k < DIN; ++k)
        acc += X[(size_t)m * DIN + k] * W[(size_t)k * DOUT + n];
    out[(size_t)m * DOUT + n] = acc;
}

extern "C" void kernel_launch(void* const* d_in, const int* in_sizes, int n_in,
                              void* d_out, int out_size, void* d_ws, size_t ws_size,
                              hipStream_t stream) {
    // setup_inputs order: X, Wq, bq, Wk, bk, Wv, bv
    const float* X  = (const float*)d_in[0];
    const float* Wv = (const float*)d_in[5];
    const float* bv = (const float*)d_in[6];
    float* out = (float*)d_out;

    const size_t xb_elems = (size_t)MROWS * DIN;
    const size_t wt_elems = (size_t)DOUT * DIN;
    const size_t needed = (xb_elems + wt_elems) * sizeof(ushort);

    if (ws_size < needed) {
        dim3 g(DOUT / 256, MROWS);
        gemm_naive<<<g, 256, 0, stream>>>(X, Wv, bv, out);
        return;
    }

    ushort* Xb = (ushort*)d_ws;
    ushort* Wt = Xb + xb_elems;

    cvt_x_kernel<<<2048, 256, 0, stream>>>(X, Xb, (int)(xb_elems / 4));
    cvt_wt_kernel<<<dim3(DOUT / 32, DIN / 32), dim3(32, 8), 0, stream>>>(Wv, Wt);
    gemm_bias<<<512, 256, 0, stream>>>(Xb, Wt, bv, out);
}

// Round 2
// 39.047 us; speedup vs baseline: 1.1435x; 1.1435x over previous
//
#include <hip/hip_runtime.h>
#include <hip/hip_bf16.h>

#define DIN  1024
#define DOUT 1024
#define MROWS 8192   // B*S = 4*2048

#define BM 256
#define BN 128
#define BK 64
#define NKT (DIN / BK)   // 16 K-tiles

typedef __attribute__((ext_vector_type(8))) short short8;
typedef __attribute__((ext_vector_type(4))) float f32x4;

__device__ __forceinline__ ushort f2bf(float f) {
    union { float f; unsigned u; } x; x.f = f;
    unsigned u = x.u + 0x7fffu + ((x.u >> 16) & 1u);  // RNE
    return (ushort)(u >> 16);
}

// ---------- pass 1a: X f32 -> bf16 (layout preserved) ----------
__global__ void cvt_x_kernel(const float* __restrict__ X, ushort* __restrict__ Xb, int n4) {
    int i = blockIdx.x * blockDim.x + threadIdx.x;
    int stride = gridDim.x * blockDim.x;
    const float4* X4 = (const float4*)X;
    ushort4* O4 = (ushort4*)Xb;
    for (int idx = i; idx < n4; idx += stride) {
        float4 v = X4[idx];
        ushort4 o;
        o.x = f2bf(v.x); o.y = f2bf(v.y); o.z = f2bf(v.z); o.w = f2bf(v.w);
        O4[idx] = o;
    }
}

// ---------- pass 1b: Wv [K][N] f32 -> WvT [N][K] bf16 (tiled transpose) ----------
__global__ void cvt_wt_kernel(const float* __restrict__ W, ushort* __restrict__ Wt) {
    __shared__ float tile[32][33];
    int bx = blockIdx.x * 32;  // n base
    int by = blockIdx.y * 32;  // k base
    int tx = threadIdx.x;      // 0..31
    int ty = threadIdx.y;      // 0..7
#pragma unroll
    for (int i = 0; i < 32; i += 8)
        tile[ty + i][tx] = W[(size_t)(by + ty + i) * DOUT + (bx + tx)];
    __syncthreads();
#pragma unroll
    for (int i = 0; i < 32; i += 8)
        Wt[(size_t)(bx + ty + i) * DIN + (by + tx)] = f2bf(tile[tx][ty + i]);
}

// ---------- pass 2: C[M][N] = Xb[M][K] @ WvT[N][K]^T + bias ----------
// 8-phase-style schedule: BK=64, 2 phases/K-tile, triple-buffered LDS (stage
// 2 tiles ahead), counted vmcnt(6) at tile boundaries (T3+T4), T2 XOR-swizzle
// via pre-swizzled global source (linear global_load_lds dest), T5 setprio.
__global__ __launch_bounds__(512, 2) void gemm_bias(
    const ushort* __restrict__ Xb,    // [8192][1024] bf16
    const ushort* __restrict__ Wt,    // [1024 n][1024 k] bf16
    const float* __restrict__ bias,   // [1024]
    float* __restrict__ out)          // [8192][1024] f32
{
    __shared__ ushort As[3][BM * BK];   // 3 x 32 KiB
    __shared__ ushort Bs[3][BN * BK];   // 3 x 16 KiB   (total 144 KiB)

    const int tid  = threadIdx.x;
    const int lane = tid & 63;
    const int wid  = tid >> 6;     // 0..7
    const int wr   = wid >> 1;     // 0..3  (wave M index, 64 rows each)
    const int wc   = wid & 1;      // 0..1  (wave N index, 64 cols each)

    // XCD-aware bijective swizzle: 256 blocks = 8 XCDs x 32.
    // Each XCD: 4 m-tiles x 8 n-tiles -> A panel 2MB + full Wt 2MB = L2-fit.
    const int bid = blockIdx.x;
    const int swz = (bid & 7) * 32 + (bid >> 3);
    const int bm = (swz >> 3) * BM;
    const int bn = (swz & 7) * BN;

    // Stage half h (h=0,1) of K-tile kt into buffer b.
    // LDS dest is LINEAR; T2 swizzle applied by XOR-permuting the global
    // source 16B-chunk column (cc ^= row&7) — rule #21 both-sides involution.
    auto stageHalf = [&](int b, int kt, int h) {
        // A half: 128 rows x 64 k = 32 KiB/2 -> 2 x 16B loads per thread
#pragma unroll
        for (int j = 0; j < 2; ++j) {
            const int c   = j * 512 + tid;      // chunk id within half (0..1023)
            const int rl  = c >> 3;             // row within half (0..127)
            const int scc = (c & 7) ^ (rl & 7); // swizzled source column chunk
            __builtin_amdgcn_global_load_lds(
                (const __attribute__((address_space(1))) void*)(Xb + (size_t)(bm + h * 128 + rl) * DIN + kt * BK + scc * 8),
                (__attribute__((address_space(3))) void*)(&As[b][h * 8192 + (j * 512 + wid * 64) * 8]),
                16, 0, 0);
        }
        // B half: 64 rows x 64 k = 16 KiB/2 -> 1 x 16B load per thread
        {
            const int c   = tid;                // 0..511
            const int rl  = c >> 3;             // row within half (0..63)
            const int scc = (c & 7) ^ (rl & 7);
            __builtin_amdgcn_global_load_lds(
                (const __attribute__((address_space(1))) void*)(Wt + (size_t)(bn + h * 64 + rl) * DIN + kt * BK + scc * 8),
                (__attribute__((address_space(3))) void*)(&Bs[b][h * 4096 + wid * 512]),
                16, 0, 0);
        }
    };

    f32x4 acc[4][4];
#pragma unroll
    for (int i = 0; i < 4; ++i)
#pragma unroll
        for (int j = 0; j < 4; ++j)
            acc[i][j] = (f32x4){0.f, 0.f, 0.f, 0.f};

    // One phase = one k-half (ks) of the current tile: 8 ds_read_b128 + optional
    // stage of one half-tile + barrier + lgkmcnt(0) + 16 MFMA + optional vmcnt.
    // wait: 0 = none, 1 = vmcnt(0), 2 = vmcnt(6).
    auto phase = [&](int buf, int ks, bool doStage, int sbuf, int skt, int sh,
                     int wait, bool endBar) {
        short8 af[4], bfr[4];
        // swizzled 16B-slot: same for every fragment (row low bits == lane&7)
        const int sc = ((ks * 4 + (lane >> 4)) ^ (lane & 7)) * 8;
        const int am = wr * 64 + (lane & 15);
        const int bnr = wc * 64 + (lane & 15);
#pragma unroll
        for (int i = 0; i < 4; ++i)
            af[i] = *(const short8*)(&As[buf][(am + i * 16) * 64 + sc]);
#pragma unroll
        for (int j = 0; j < 4; ++j)
            bfr[j] = *(const short8*)(&Bs[buf][(bnr + j * 16) * 64 + sc]);
        if (doStage) stageHalf(sbuf, skt, sh);
        __builtin_amdgcn_s_barrier();
        asm volatile("s_waitcnt lgkmcnt(0)" ::: "memory");
        __builtin_amdgcn_sched_barrier(0);
        __builtin_amdgcn_s_setprio(1);
#pragma unroll
        for (int i = 0; i < 4; ++i)
#pragma unroll
            for (int j = 0; j < 4; ++j)
                acc[i][j] = __builtin_amdgcn_mfma_f32_16x16x32_bf16(af[i], bfr[j], acc[i][j], 0, 0, 0);
        __builtin_amdgcn_s_setprio(0);
        if (wait == 2)      asm volatile("s_waitcnt vmcnt(6)" ::: "memory");
        else if (wait == 1) asm volatile("s_waitcnt vmcnt(0)" ::: "memory");
        if (endBar) __builtin_amdgcn_s_barrier();
    };

    // ---- prologue: stage tiles 0 and 1 (12 loads/thread), wait tile 0 ----
    stageHalf(0, 0, 0);
    stageHalf(0, 0, 1);
    stageHalf(1, 1, 0);
    stageHalf(1, 1, 1);
    asm volatile("s_waitcnt vmcnt(6)" ::: "memory");   // tile 0 landed, tile 1 in flight
    __builtin_amdgcn_s_barrier();

    // ---- main loop: compute tile t, stage tile t+2 (buffer of t-1) ----
    for (int t = 0; t < NKT - 2; ++t) {                // t = 0..13
        const int buf  = t % 3;
        const int sbuf = (t + 2) % 3;
        phase(buf, 0, true, sbuf, t + 2, 0, 0, true);
        phase(buf, 1, true, sbuf, t + 2, 1, 2, true);  // vmcnt(6): t+1 landed
    }
    // t = 14: nothing left to stage; drain tile-15 loads at the boundary
    phase((NKT - 2) % 3, 0, false, 0, 0, 0, 0, true);
    phase((NKT - 2) % 3, 1, false, 0, 0, 0, 1, true);  // vmcnt(0)
    // t = 15: last tile
    phase((NKT - 1) % 3, 0, false, 0, 0, 0, 0, true);
    phase((NKT - 1) % 3, 1, false, 0, 0, 0, 0, false);

    // ---- epilogue: bias + store. C/D layout: col = lane&15, row = (lane>>4)*4 + r ----
    const int crow = bm + wr * 64 + (lane >> 4) * 4;
    const int ccol = bn + wc * 64 + (lane & 15);
#pragma unroll
    for (int j = 0; j < 4; ++j) {
        const int col = ccol + j * 16;
        const float bval = bias[col];
#pragma unroll
        for (int i = 0; i < 4; ++i) {
#pragma unroll
            for (int r = 0; r < 4; ++r)
                out[(size_t)(crow + i * 16 + r) * DOUT + col] = acc[i][j][r] + bval;
        }
    }
}

// ---------- fallback (only if workspace too small): naive f32 ----------
__global__ void gemm_naive(const float* __restrict__ X, const float* __restrict__ W,
                           const float* __restrict__ b, float* __restrict__ out) {
    int n = blockIdx.x * blockDim.x + threadIdx.x;
    int m = blockIdx.y;
    float acc = b[n];
    for (int k = 0; k < DIN; ++k)
        acc += X[(size_t)m * DIN + k] * W[(size_t)k * DOUT + n];
    out[(size_t)m * DOUT + n] = acc;
}

extern "C" void kernel_launch(void* const* d_in, const int* in_sizes, int n_in,
                              void* d_out, int out_size, void* d_ws, size_t ws_size,
                              hipStream_t stream) {
    // setup_inputs order: X, Wq, bq, Wk, bk, Wv, bv
    const float* X  = (const float*)d_in[0];
    const float* Wv = (const float*)d_in[5];
    const float* bv = (const float*)d_in[6];
    float* out = (float*)d_out;

    const size_t xb_elems = (size_t)MROWS * DIN;
    const size_t wt_elems = (size_t)DOUT * DIN;
    const size_t needed = (xb_elems + wt_elems) * sizeof(ushort);

    if (ws_size < needed) {
        dim3 g(DOUT / 256, MROWS);
        gemm_naive<<<g, 256, 0, stream>>>(X, Wv, bv, out);
        return;
    }

    ushort* Xb = (ushort*)d_ws;
    ushort* Wt = Xb + xb_elems;

    cvt_x_kernel<<<2048, 256, 0, stream>>>(X, Xb, (int)(xb_elems / 4));
    cvt_wt_kernel<<<dim3(DOUT / 32, DIN / 32), dim3(32, 8), 0, stream>>>(Wv, Wt);
    gemm_bias<<<256, 512, 0, stream>>>(Xb, Wt, bv, out);
}